// Round 13
// baseline (41851.526 us; speedup 1.0000x reference)
//
#include <hip/hip_runtime.h>
#include <stdint.h>

#define NT 256
#define BAR_GROUPS 16

struct P {
    const float *actions, *embeds, *aw, *ab, *ag, *abt;
    const float *w_ih, *w_hh, *b_ih, *b_hh;
    const float *pr_w1, *pr_b1, *pr_g, *pr_bt, *pr_w2, *pr_b2;
    const float *po_w1, *po_b1, *po_g, *po_bt, *po_w2, *po_b2;
    float *out_states, *out_priors, *out_posts;
    float *WT;          // [1024][1536] w_ih stoch-part transposed
    double *deter;      // [512][512]
    double *gh, *gi;    // [512][1536]
    double *POraw;      // [512][512]
    double *PRraw;      // [512][512]
    double *At0, *At1;  // [512][512]
    int *sidx;          // [512*32]
    int *bar;           // hierarchical barrier state (1024 ints)
};

// ---------------- math helpers (f64) ---------------------------------------

__device__ __forceinline__ double mish_d(double x) {
    double sp = fmax(x, 0.0) + log1p(exp(-fabs(x)));
    return x * tanh(sp);
}

// ---------------- threefry2x32 (JAX partitionable semantics) ----------------

__device__ __forceinline__ uint32_t rotl32(uint32_t v, int r) {
    return (v << r) | (v >> (32 - r));
}

__device__ __forceinline__ void tf2x32(uint32_t k0, uint32_t k1, uint32_t& x0, uint32_t& x1) {
    const uint32_t ks2 = k0 ^ k1 ^ 0x1BD11BDAu;
    const int ra[4] = {13, 15, 26, 6};
    const int rb[4] = {17, 29, 16, 24};
    x0 += k0; x1 += k1;
#pragma unroll
    for (int i = 0; i < 4; i++) { x0 += x1; x1 = rotl32(x1, ra[i]); x1 ^= x0; }
    x0 += k1; x1 += ks2 + 1u;
#pragma unroll
    for (int i = 0; i < 4; i++) { x0 += x1; x1 = rotl32(x1, rb[i]); x1 ^= x0; }
    x0 += ks2; x1 += k0 + 2u;
#pragma unroll
    for (int i = 0; i < 4; i++) { x0 += x1; x1 = rotl32(x1, ra[i]); x1 ^= x0; }
    x0 += k0; x1 += k1 + 3u;
#pragma unroll
    for (int i = 0; i < 4; i++) { x0 += x1; x1 = rotl32(x1, rb[i]); x1 ^= x0; }
    x0 += k1; x1 += ks2 + 4u;
#pragma unroll
    for (int i = 0; i < 4; i++) { x0 += x1; x1 = rotl32(x1, ra[i]); x1 ^= x0; }
    x0 += ks2; x1 += k0 + 5u;
}

__device__ __forceinline__ void step_key(int t, uint32_t& ka, uint32_t& kb) {
    uint32_t x0 = 0u, x1 = (uint32_t)t;
    tf2x32(0u, 42u, x0, x1);
    ka = x0; kb = x1;
}

__device__ __forceinline__ double gumbel_d(uint32_t n, uint32_t ka, uint32_t kb) {
    uint32_t x0 = 0u, x1 = n;
    tf2x32(ka, kb, x0, x1);
    uint32_t bits = x0 ^ x1;
    uint32_t fb = (bits >> 9) | 0x3f800000u;
    float f = __uint_as_float(fb) - 1.0f;
    double u = fmax((double)f, 1.17549435e-38);
    return -log(-log(u));
}

// ---------------- two-level grid barrier (timeout-abort) ---------------------
// bar layout (ints): cnt[g] at g*32 (g<16), root at 512, gen at 544, abort at 576.

__device__ bool xbar(int* B, int* aflag_s) {
    __syncthreads();
    if (threadIdx.x == 0) {
        __threadfence();
        int g = __hip_atomic_load(B + 544, __ATOMIC_RELAXED, __HIP_MEMORY_SCOPE_AGENT);
        int grp = blockIdx.x & (BAR_GROUPS - 1);
        int gsz = (int)gridDim.x / BAR_GROUPS;
        int a = __hip_atomic_fetch_add(B + grp * 32, 1, __ATOMIC_ACQ_REL, __HIP_MEMORY_SCOPE_AGENT);
        if (a == gsz - 1) {
            __hip_atomic_store(B + grp * 32, 0, __ATOMIC_RELAXED, __HIP_MEMORY_SCOPE_AGENT);
            int r = __hip_atomic_fetch_add(B + 512, 1, __ATOMIC_ACQ_REL, __HIP_MEMORY_SCOPE_AGENT);
            if (r == BAR_GROUPS - 1) {
                __hip_atomic_store(B + 512, 0, __ATOMIC_RELAXED, __HIP_MEMORY_SCOPE_AGENT);
                __hip_atomic_fetch_add(B + 544, 1, __ATOMIC_RELEASE, __HIP_MEMORY_SCOPE_AGENT);
            }
        }
        uint64_t t0 = __builtin_amdgcn_s_memrealtime();
        while (__hip_atomic_load(B + 544, __ATOMIC_ACQUIRE, __HIP_MEMORY_SCOPE_AGENT) == g) {
            __builtin_amdgcn_s_sleep(1);
            if (__hip_atomic_load(B + 576, __ATOMIC_RELAXED, __HIP_MEMORY_SCOPE_AGENT)) break;
            if (__builtin_amdgcn_s_memrealtime() - t0 > 100000000ULL) {
                __hip_atomic_store(B + 576, 1, __ATOMIC_RELAXED, __HIP_MEMORY_SCOPE_AGENT);
                break;
            }
        }
        __threadfence();
        *aflag_s = __hip_atomic_load(B + 576, __ATOMIC_RELAXED, __HIP_MEMORY_SCOPE_AGENT);
    }
    __syncthreads();
    return *aflag_s == 0;
}

// ---------------- per-wave row ops ------------------------------------------

__device__ void act_row(const float* actions, const float* aw, const float* ab,
                        const float* ag, const float* abt, double* dst, int b, int t) {
    int l = threadIdx.x & 63;
    double x[8];
    double s = 0;
#pragma unroll
    for (int i = 0; i < 8; i++) {
        int h = l + 64 * i;
        double a = (double)ab[h];
        if (t > 0) {
            const float* ac = actions + ((long long)b * 64 + (t - 1)) * 32;
            #pragma unroll 4
            for (int k = 0; k < 32; k++)
                a += (double)ac[k] * (double)aw[h * 32 + k];
        }
        x[i] = a; s += a;
    }
#pragma unroll
    for (int m = 1; m < 64; m <<= 1) s += __shfl_xor(s, m);
    double mean = s * (1.0 / 512.0);
    double vv = 0;
#pragma unroll
    for (int i = 0; i < 8; i++) { double d = x[i] - mean; vv += d * d; }
#pragma unroll
    for (int m = 1; m < 64; m <<= 1) vv += __shfl_xor(vv, m);
    double inv = 1.0 / sqrt(vv * (1.0 / 512.0) + 1e-5);
#pragma unroll
    for (int i = 0; i < 8; i++) {
        int h = l + 64 * i;
        dst[h] = mish_d((x[i] - mean) * inv * (double)ag[h] + (double)abt[h]);
    }
}

__device__ void ln_row(double* row, const float* g, const float* bt) {
    int l = threadIdx.x & 63;
    double x[8];
    double s = 0;
#pragma unroll
    for (int i = 0; i < 8; i++) { x[i] = row[l + 64 * i]; s += x[i]; }
#pragma unroll
    for (int m = 1; m < 64; m <<= 1) s += __shfl_xor(s, m);
    double mean = s * (1.0 / 512.0);
    double vv = 0;
#pragma unroll
    for (int i = 0; i < 8; i++) { double d = x[i] - mean; vv += d * d; }
#pragma unroll
    for (int m = 1; m < 64; m <<= 1) vv += __shfl_xor(vv, m);
    double inv = 1.0 / sqrt(vv * (1.0 / 512.0) + 1e-5);
#pragma unroll
    for (int i = 0; i < 8; i++) {
        int h = l + 64 * i;
        row[h] = mish_d((x[i] - mean) * inv * (double)g[h] + (double)bt[h]);
    }
}

// ---------------- 64x32 tile, K=512, dbuf slice=8 (vector f64) --------------

__device__ void tile6432(const double* __restrict__ Ad, long long lda,
                         const float* __restrict__ Bp, long long ldb,
                         int m0, int n0,
                         double (&AsD)[2][640], float (&BsF)[2][640],
                         double (&c)[2][4]) {
    const int tid = threadIdx.x;
    const int ty = tid >> 3, tx = tid & 7;
    const int ar = tid >> 2, ak = (tid & 3) * 2;   // A: 64 rows x 8k, 2/thread
    const int br = tid >> 3, bk = tid & 7;         // B: 32 rows x 8k, 1/thread
#pragma unroll
    for (int i = 0; i < 2; i++)
#pragma unroll
        for (int j = 0; j < 4; j++) c[i][j] = 0.0;
    double ra[2]; float rb;
#pragma unroll
    for (int i = 0; i < 2; i++) ra[i] = Ad[(long long)(m0 + ar) * lda + ak + i];
    rb = Bp[(long long)(n0 + br) * ldb + bk];
#pragma unroll
    for (int i = 0; i < 2; i++) AsD[0][ar * 9 + ak + i] = ra[i];
    BsF[0][br * 9 + bk] = rb;
    __syncthreads();
    int cur = 0;
    for (int kb = 0; kb < 64; kb++) {
        if (kb < 63) {
            int k0 = (kb + 1) * 8;
#pragma unroll
            for (int i = 0; i < 2; i++) ra[i] = Ad[(long long)(m0 + ar) * lda + k0 + ak + i];
            rb = Bp[(long long)(n0 + br) * ldb + k0 + bk];
        }
#pragma unroll
        for (int kk = 0; kk < 8; kk++) {
            double av[2], bv[4];
#pragma unroll
            for (int i = 0; i < 2; i++) av[i] = AsD[cur][(ty * 2 + i) * 9 + kk];
#pragma unroll
            for (int j = 0; j < 4; j++) bv[j] = (double)BsF[cur][(tx * 4 + j) * 9 + kk];
#pragma unroll
            for (int i = 0; i < 2; i++)
#pragma unroll
                for (int j = 0; j < 4; j++) c[i][j] = fma(av[i], bv[j], c[i][j]);
        }
        if (kb < 63) {
            int nx = cur ^ 1;
#pragma unroll
            for (int i = 0; i < 2; i++) AsD[nx][ar * 9 + ak + i] = ra[i];
            BsF[nx][br * 9 + bk] = rb;
        }
        __syncthreads();
        cur ^= 1;
    }
}

// ---------------- 32x32 tile, generic K, dbuf slice=16 (vector f64) ---------

__device__ void tile32(const double* Ad, long long ldad,
                       const float* Af, long long ldaf, int asplit,
                       const float* Bp, long long ldb, int K,
                       int m0, int n0,
                       double (&AsD)[2][640], float (&BsF)[2][640],
                       double* c) {
    const int tid = threadIdx.x;
    const int ty = tid >> 3, tx = tid & 7;
    const int sr = tid >> 3, sk = (tid & 7) * 2;
    double ra[2]; float rb[2];
#pragma unroll
    for (int i = 0; i < 2; i++) {
        int k = sk + i;
        ra[i] = (k < asplit) ? Ad[(long long)(m0 + sr) * ldad + k]
                             : (double)Af[(long long)(m0 + sr) * ldaf + (k - asplit)];
        rb[i] = Bp[(long long)(n0 + sr) * ldb + k];
    }
#pragma unroll
    for (int i = 0; i < 2; i++) { AsD[0][sr * 17 + sk + i] = ra[i]; BsF[0][sr * 17 + sk + i] = rb[i]; }
    __syncthreads();
    c[0] = c[1] = c[2] = c[3] = 0.0;
    const int nkb = K >> 4;
    int cur = 0;
    for (int kb = 0; kb < nkb; kb++) {
        if (kb + 1 < nkb) {
            int k0 = (kb + 1) << 4;
#pragma unroll
            for (int i = 0; i < 2; i++) {
                int k = k0 + sk + i;
                ra[i] = (k < asplit) ? Ad[(long long)(m0 + sr) * ldad + k]
                                     : (double)Af[(long long)(m0 + sr) * ldaf + (k - asplit)];
                rb[i] = Bp[(long long)(n0 + sr) * ldb + k];
            }
        }
#pragma unroll
        for (int kk = 0; kk < 16; kk++) {
            double a = AsD[cur][ty * 17 + kk];
            c[0] = fma(a, (double)BsF[cur][(tx * 4 + 0) * 17 + kk], c[0]);
            c[1] = fma(a, (double)BsF[cur][(tx * 4 + 1) * 17 + kk], c[1]);
            c[2] = fma(a, (double)BsF[cur][(tx * 4 + 2) * 17 + kk], c[2]);
            c[3] = fma(a, (double)BsF[cur][(tx * 4 + 3) * 17 + kk], c[3]);
        }
        if (kb + 1 < nkb) {
            int nx = cur ^ 1;
#pragma unroll
            for (int i = 0; i < 2; i++) { AsD[nx][sr * 17 + sk + i] = ra[i]; BsF[nx][sr * 17 + sk + i] = rb[i]; }
        }
        __syncthreads();
        cur ^= 1;
    }
}

// ---------------- epilogues (register-only, 8-lane-group shuffles) ----------

__device__ void unimix_fin(const double* c, const float* bias, float* out,
                           int m0, int n0, int t) {
    const int ty = threadIdx.x >> 3, tx = threadIdx.x & 7;
    double va[4];
#pragma unroll
    for (int q = 0; q < 4; q++) va[q] = c[q] + (double)bias[n0 + tx * 4 + q];
    double mx = fmax(fmax(va[0], va[1]), fmax(va[2], va[3]));
#pragma unroll
    for (int m = 1; m < 8; m <<= 1) mx = fmax(mx, __shfl_xor(mx, m));
    double sum = 0;
#pragma unroll
    for (int q = 0; q < 4; q++) sum += exp(va[q] - mx);
#pragma unroll
    for (int m = 1; m < 8; m <<= 1) sum += __shfl_xor(sum, m);
    double rinv = 1.0 / sum;
    long long row = (long long)(m0 + ty) * 64 + t;
    float4 o;
    float* po = (float*)&o;
#pragma unroll
    for (int q = 0; q < 4; q++)
        po[q] = (float)log(0.99 * (exp(va[q] - mx) * rinv) + 0.01 / 32.0);
    *(float4*)(out + row * 1024 + n0 + tx * 4) = o;
}

__device__ void sample_fin(const double* c, const P& p, int t, int m0, int n0) {
    const int ty = threadIdx.x >> 3, tx = threadIdx.x & 7;
    int b = m0 + ty;
    double va[4];
#pragma unroll
    for (int q = 0; q < 4; q++) va[q] = c[q] + (double)p.po_b2[n0 + tx * 4 + q];
    double mx = fmax(fmax(va[0], va[1]), fmax(va[2], va[3]));
#pragma unroll
    for (int m = 1; m < 8; m <<= 1) mx = fmax(mx, __shfl_xor(mx, m));
    double sum = 0;
#pragma unroll
    for (int q = 0; q < 4; q++) sum += exp(va[q] - mx);
#pragma unroll
    for (int m = 1; m < 8; m <<= 1) sum += __shfl_xor(sum, m);
    double rinv = 1.0 / sum;
    uint32_t ka, kb;
    step_key(t, ka, kb);
    float4 o;
    float* po = (float*)&o;
    double bv = -1e300; int bc = 0;
#pragma unroll
    for (int q = 0; q < 4; q++) {
        int cc = tx * 4 + q;
        double lp = log(0.99 * (exp(va[q] - mx) * rinv) + 0.01 / 32.0);
        po[q] = (float)lp;
        double val = gumbel_d((uint32_t)(b * 1024 + n0 + cc), ka, kb) + lp;
        if (val > bv) { bv = val; bc = cc; }
    }
#pragma unroll
    for (int m = 1; m < 8; m <<= 1) {
        double ov = __shfl_xor(bv, m);
        int oc = __shfl_xor(bc, m);
        if (ov > bv || (ov == bv && oc < bc)) { bv = ov; bc = oc; }
    }
    *(float4*)(p.out_posts + ((long long)b * 64 + t) * 1024 + n0 + tx * 4) = o;
    float4 oh;
    oh.x = (tx * 4 + 0 == bc) ? 1.0f : 0.0f;
    oh.y = (tx * 4 + 1 == bc) ? 1.0f : 0.0f;
    oh.z = (tx * 4 + 2 == bc) ? 1.0f : 0.0f;
    oh.w = (tx * 4 + 3 == bc) ? 1.0f : 0.0f;
    *(float4*)(p.out_states + ((long long)b * 64 + t) * 1536 + 512 + n0 + tx * 4) = oh;
    if (tx == 0) p.sidx[b * 32 + (n0 >> 5)] = bc;
}

// ---------------- the cooperative mega kernel -------------------------------

__global__ __launch_bounds__(NT, 4) void k_mega(P p) {
    __shared__ double AsD[2][640];
    __shared__ float  BsF[2][640];
    __shared__ int aflag;
    const int bid = blockIdx.x, tid = threadIdx.x;
    const int nb = gridDim.x;
    double c4[4];
    double c[2][4];

    // ---- P0: WT transpose, zero deter, At0 rows for t=0 ----
    for (int i = bid * NT + tid; i < 1024 * 1536; i += nb * NT) {
        int cc = i / 1536, n = i % 1536;
        p.WT[(long long)cc * 1536 + n] = p.w_ih[(long long)n * 1536 + cc];
    }
    for (int i = bid * NT + tid; i < 512 * 512; i += nb * NT) p.deter[i] = 0.0;
    for (int m = bid * 4 + (tid >> 6); m < 512; m += nb * 4)
        act_row(p.actions, p.aw, p.ab, p.ag, p.abt, p.At0 + (long long)m * 512, m, 0);
    if (!xbar(p.bar, &aflag)) return;

    // ---- P1: 64 sequential steps ----
    for (int t = 0; t < 64; t++) {
        const double* At = (t & 1) ? p.At1 : p.At0;
        double* Atn = (t & 1) ? p.At0 : p.At1;

        // phase A: gh 64x32 (384) + gi 64x32 (384, + one-hot gather) + act t+1 (128)
        for (int q = bid; q < 896; q += nb) {
            if (q < 384) {
                int tm = q / 48, tn = q % 48;
                int m0 = tm * 64, n0 = tn * 32;
                tile6432(p.deter, 512, p.w_hh, 512, m0, n0, AsD, BsF, c);
                const int ty = tid >> 3, tx = tid & 7;
#pragma unroll
                for (int i = 0; i < 2; i++) {
                    long long mr = m0 + ty * 2 + i;
#pragma unroll
                    for (int j = 0; j < 4; j++) {
                        int n = n0 + tx * 4 + j;
                        p.gh[mr * 1536 + n] = c[i][j] + (double)p.b_hh[n];
                    }
                }
            } else if (q < 768) {
                int q2 = q - 384;
                int tm = q2 / 48, tn = q2 % 48;
                int m0 = tm * 64, n0 = tn * 32;
                tile6432(At, 512, p.w_ih + 1024, 1536, m0, n0, AsD, BsF, c);
                const int ty = tid >> 3, tx = tid & 7;
                if (t > 0) {
                    // stage this tile's sidx rows into LDS (flat AsD = 10240B >= 8192B)
                    int* sx = (int*)&AsD[0][0];
                    __syncthreads();
                    for (int i = tid; i < 64 * 32; i += NT)
                        sx[i] = p.sidx[(m0 + (i >> 5)) * 32 + (i & 31)];
                    __syncthreads();
#pragma unroll
                    for (int i = 0; i < 2; i++) {
                        int r = ty * 2 + i;
                        for (int s = 0; s < 32; s++) {
                            int cc = s * 32 + sx[r * 32 + s];
                            const float4 v = *(const float4*)(p.WT + (long long)cc * 1536 + n0 + tx * 4);
                            c[i][0] += (double)v.x; c[i][1] += (double)v.y;
                            c[i][2] += (double)v.z; c[i][3] += (double)v.w;
                        }
                    }
                    __syncthreads();
                }
#pragma unroll
                for (int i = 0; i < 2; i++) {
                    long long mr = m0 + ty * 2 + i;
#pragma unroll
                    for (int j = 0; j < 4; j++) {
                        int n = n0 + tx * 4 + j;
                        p.gi[mr * 1536 + n] = c[i][j] + (double)p.b_ih[n];
                    }
                }
            } else {
                if (t < 63) {
                    int rr = (q - 768) * 4 + (tid >> 6);
                    act_row(p.actions, p.aw, p.ab, p.ag, p.abt,
                            Atn + (long long)rr * 512, rr, t + 1);
                }
            }
        }
        if (!xbar(p.bar, &aflag)) return;

        // phase B: GRU pointwise
        for (int e = bid * NT + tid; e < 512 * 512; e += nb * NT) {
            int b = e >> 9, d = e & 511;
            long long base = (long long)b * 1536;
            double ir = p.gi[base + d],          hr = p.gh[base + d];
            double iz = p.gi[base + 512 + d],    hz = p.gh[base + 512 + d];
            double in_ = p.gi[base + 1024 + d],  hn = p.gh[base + 1024 + d];
            double h = p.deter[e];
            double rr = 1.0 / (1.0 + exp(-(ir + hr)));
            double zz = 1.0 / (1.0 + exp(-(iz + hz)));
            double nn = tanh(in_ + rr * hn);
            double dn = (1.0 - zz) * nn + zz * h;
            p.deter[e] = dn;
            p.out_states[((long long)b * 64 + t) * 1536 + d] = (float)dn;
        }
        if (!xbar(p.bar, &aflag)) return;

        // phase C: posterior hidden (K=1024, 256 tiles) + prior hidden (256 tiles)
        for (int q = bid; q < 512; q += nb) {
            if (q < 256) {
                int tm = q >> 4, tn = q & 15;
                tile32(p.deter, 512, p.embeds + (long long)t * 512, 32768, 512,
                       p.po_w1, 1024, 1024, tm * 32, tn * 32, AsD, BsF, c4);
                const int ty = tid >> 3, tx = tid & 7;
#pragma unroll
                for (int j = 0; j < 4; j++)
                    p.POraw[(long long)(tm * 32 + ty) * 512 + tn * 32 + tx * 4 + j] =
                        c4[j] + (double)p.po_b1[tn * 32 + tx * 4 + j];
            } else {
                int q2 = q - 256;
                int tm = q2 >> 4, tn = q2 & 15;
                tile32(p.deter, 512, nullptr, 0, 512, p.pr_w1, 512, 512,
                       tm * 32, tn * 32, AsD, BsF, c4);
                const int ty = tid >> 3, tx = tid & 7;
#pragma unroll
                for (int j = 0; j < 4; j++)
                    p.PRraw[(long long)(tm * 32 + ty) * 512 + tn * 32 + tx * 4 + j] =
                        c4[j] + (double)p.pr_b1[tn * 32 + tx * 4 + j];
            }
        }
        if (!xbar(p.bar, &aflag)) return;

        // phase D: LN+mish rows (512 po + 512 pr)
        for (int r = bid * 4 + (tid >> 6); r < 1024; r += nb * 4) {
            if (r < 512) ln_row(p.POraw + (long long)r * 512, p.po_g, p.po_bt);
            else         ln_row(p.PRraw + (long long)(r - 512) * 512, p.pr_g, p.pr_bt);
        }
        if (!xbar(p.bar, &aflag)) return;

        // phase E: posterior out + sample (512) ; prior out + unimix (512)
        for (int q = bid; q < 1024; q += nb) {
            if (q < 512) {
                int tm = q >> 5, s = q & 31;
                tile32(p.POraw, 512, nullptr, 0, 512, p.po_w2, 512, 512,
                       tm * 32, s * 32, AsD, BsF, c4);
                sample_fin(c4, p, t, tm * 32, s * 32);
            } else {
                int q2 = q - 512;
                int tm = q2 >> 5, s = q2 & 31;
                tile32(p.PRraw, 512, nullptr, 0, 512, p.pr_w2, 512, 512,
                       tm * 32, s * 32, AsD, BsF, c4);
                unimix_fin(c4, p.pr_b2, p.out_priors, tm * 32, s * 32, t);
            }
        }
        if (!xbar(p.bar, &aflag)) return;
    }
}

__global__ void k_init(int* bar) {
    for (int i = threadIdx.x; i < 1024; i += 64) bar[i] = 0;
}

// ---------------- host -------------------------------------------------------

extern "C" void kernel_launch(void* const* d_in, const int* in_sizes, int n_in,
                              void* d_out, int out_size, void* d_ws, size_t ws_size,
                              hipStream_t stream) {
    P p;
    p.actions = (const float*)d_in[0];
    p.embeds  = (const float*)d_in[1];
    p.aw = (const float*)d_in[2];  p.ab = (const float*)d_in[3];
    p.ag = (const float*)d_in[4];  p.abt = (const float*)d_in[5];
    p.w_ih = (const float*)d_in[6]; p.w_hh = (const float*)d_in[7];
    p.b_ih = (const float*)d_in[8]; p.b_hh = (const float*)d_in[9];
    p.pr_w1 = (const float*)d_in[10]; p.pr_b1 = (const float*)d_in[11];
    p.pr_g = (const float*)d_in[12];  p.pr_bt = (const float*)d_in[13];
    p.pr_w2 = (const float*)d_in[14]; p.pr_b2 = (const float*)d_in[15];
    p.po_w1 = (const float*)d_in[16]; p.po_b1 = (const float*)d_in[17];
    p.po_g = (const float*)d_in[18];  p.po_bt = (const float*)d_in[19];
    p.po_w2 = (const float*)d_in[20]; p.po_b2 = (const float*)d_in[21];

    float* out = (float*)d_out;
    p.out_states = out;
    p.out_priors = out + (size_t)512 * 64 * 1536;
    p.out_posts  = out + (size_t)512 * 64 * 1536 + (size_t)512 * 64 * 1024;

    char* ws = (char*)d_ws;
    size_t off = 0;
    auto carve = [&](size_t bytes) -> char* {
        char* q = ws + off;
        off = (off + bytes + 255) & ~(size_t)255;
        return q;
    };
    p.bar   = (int*)carve(4096);
    p.sidx  = (int*)carve((size_t)512 * 32 * 4);
    p.WT    = (float*)carve((size_t)1024 * 1536 * 4);
    p.deter = (double*)carve((size_t)512 * 512 * 8);
    p.gh    = (double*)carve((size_t)512 * 1536 * 8);
    p.gi    = (double*)carve((size_t)512 * 1536 * 8);
    p.POraw = (double*)carve((size_t)512 * 512 * 8);
    p.PRraw = (double*)carve((size_t)512 * 512 * 8);
    p.At0   = (double*)carve((size_t)512 * 512 * 8);
    p.At1   = (double*)carve((size_t)512 * 512 * 8);
    if (off > ws_size) return;  // fast visible failure

    // Pick the largest grid the cooperative-launch validator will accept.
    int maxb = 0;
    hipError_t oe = hipOccupancyMaxActiveBlocksPerMultiprocessor(
        &maxb, (const void*)k_mega, NT, 0);
    if (oe != hipSuccess || maxb < 1) maxb = 1;
    if (maxb > 4) maxb = 4;
    int nb = 256 * maxb;   // multiple of BAR_GROUPS (16)

    k_init<<<1, 64, 0, stream>>>(p.bar);
    void* args[] = { (void*)&p };
    hipLaunchCooperativeKernel((const void*)k_mega, dim3(nb), dim3(NT),
                               args, 0, stream);
}